// Round 12
// baseline (584.254 us; speedup 1.0000x reference)
//
#include <hip/hip_runtime.h>
#include <math.h>

#define NPOS  16384
#define LBAG  30
#define NFEAT 40960
#define HDIM  512          // per side
#define MT    16           // positions per block (mlp2)

typedef short bf16x8 __attribute__((ext_vector_type(8)));
typedef float f32x4  __attribute__((ext_vector_type(4)));

__device__ __forceinline__ unsigned int f2bf(float f) {
    unsigned int u = __float_as_uint(f);
    return (u + 0x7fffu + ((u >> 16) & 1u)) >> 16;
}
__device__ __forceinline__ float clip01(float v) { return fminf(fmaxf(v, 0.f), 1.f); }

// ---------------------------------------------------------------------------
// Prep 1: emb fp32 -> bf16 single table [NFEAT][512] (uint pairs). ~20us.
// ---------------------------------------------------------------------------
__global__ __launch_bounds__(256) void cvt_emb(const float* __restrict__ src,
                                               unsigned int* __restrict__ dst) {
    const int nchunk = NFEAT * HDIM / 8;
    int c = blockIdx.x * 256 + threadIdx.x;
    const int stride = gridDim.x * 256;
    for (; c < nchunk; c += stride) {
        float4 f0 = ((const float4*)src)[(size_t)c * 2];
        float4 f1 = ((const float4*)src)[(size_t)c * 2 + 1];
        uint4 o;
        o.x = f2bf(f0.x) | (f2bf(f0.y) << 16);
        o.y = f2bf(f0.z) | (f2bf(f0.w) << 16);
        o.z = f2bf(f1.x) | (f2bf(f1.y) << 16);
        o.w = f2bf(f1.z) | (f2bf(f1.w) << 16);
        ((uint4*)dst)[c] = o;
    }
}

// ---------------------------------------------------------------------------
// Prep 2: W1 [128][1024] fp32 -> bf16 in MFMA B-fragment order.
//   B[k][j] = W1[j][k], j = nf*16 + (lane&15), k = ks*32 + (lane>>4)*8 + b
// ---------------------------------------------------------------------------
__global__ __launch_bounds__(256) void prep_w1(const float* __restrict__ W1,
                                               unsigned int* __restrict__ dst) {
    int c = blockIdx.x * 256 + threadIdx.x;
    if (c >= 8 * 32 * 64) return;
    int l  = c & 63;
    int ks = (c >> 6) & 31;
    int nf = c >> 11;
    int o  = nf * 16 + (l & 15);
    int kb = ks * 32 + (l >> 4) * 8;
    float4 f0 = *(const float4*)(W1 + (size_t)o * 1024 + kb);
    float4 f1 = *(const float4*)(W1 + (size_t)o * 1024 + kb + 4);
    uint4 v;
    v.x = f2bf(f0.x) | (f2bf(f0.y) << 16);
    v.y = f2bf(f0.z) | (f2bf(f0.w) << 16);
    v.z = f2bf(f1.x) | (f2bf(f1.y) << 16);
    v.w = f2bf(f1.z) | (f2bf(f1.w) << 16);
    ((uint4*)dst)[c] = v;
}

// ---------------------------------------------------------------------------
// Kernel 1, round 12: r10's XCD-sliced gather (the best: 78us) + DUAL
// independent accumulator chains. Evidence r6->r10: gather throughput scales
// with total outstanding misses/CU (16->32 waves = 1.8x); r10 sat at ~1 load
// in flight/wave because the single fp32 acc chain serializes (VGPR=16).
// r11 (deep pipe, 16 waves) regressed - depth must not cost waves.
// Here: rows split even/odd into ac0/ac1 (fp32 reassociation ~1e-7, vs 2e-3
// bf16 floor - fine), pair-loop fully unrolled, __launch_bounds__(256,8)
// caps VGPR at 64 so 8 blocks/CU (32 waves) are preserved while the
// allocator can hold 2-4 loads in flight per wave.
// ---------------------------------------------------------------------------
__global__ __launch_bounds__(256, 8) void gather_slices(
    const int* __restrict__ stm_idx, const int* __restrict__ nstm_idx,
    const unsigned int* __restrict__ embbf,     // [NFEAT][256] uints (512 bf16)
    unsigned int* __restrict__ xg)              // [NPOS][512] uints, swizzled
{
    __shared__ int sidx[3840];                  // 64 pos x 2 sides x 30
    const int t     = threadIdx.x;
    const int slice = blockIdx.x & 7;
    const int pblk  = (blockIdx.x >> 3) * 64;

    // stage indices, bag-major: sidx[(p*2+side)*30 + r]
#pragma unroll
    for (int i = 0; i < 15; ++i) {
        int e = t + i * 256;                    // 0..3839
        if (e < 1920) {
            int p = e / 30, r = e - p * 30;
            sidx[p * 60 + r] = stm_idx[(pblk + p) * 30 + r];
        } else {
            int e2 = e - 1920;
            int p = e2 / 30, r = e2 - p * 30;
            sidx[p * 60 + 30 + r] = nstm_idx[(pblk + p) * 30 + r];
        }
    }
    __syncthreads();

    const int lane = t & 63, w = t >> 6;
    const int g  = lane >> 3;                   // lane-group 0..7 (one bag)
    const int li = lane & 7;                    // 16B chunk within 128B line
    const unsigned int tabofs = slice * 32 + li * 4;

#pragma unroll 1
    for (int it = 0; it < 4; ++it) {
        const int bag  = it * 32 + w * 8 + g;   // 0..127
        const int p    = bag >> 1;
        const int side = bag & 1;
        const int* ids = sidx + bag * 30;       // banks 30g%32: all distinct
        float ac0[8], ac1[8];
#pragma unroll
        for (int j = 0; j < 8; ++j) { ac0[j] = 0.f; ac1[j] = 0.f; }
#pragma unroll
        for (int r = 0; r < 30; r += 2) {
            const int id0 = ids[r];
            const int id1 = ids[r + 1];
            const uint4 v0 = *(const uint4*)(embbf + (size_t)id0 * 256 + tabofs);
            const uint4 v1 = *(const uint4*)(embbf + (size_t)id1 * 256 + tabofs);
            ac0[0] += __uint_as_float(v0.x << 16);
            ac0[1] += __uint_as_float(v0.x & 0xffff0000u);
            ac0[2] += __uint_as_float(v0.y << 16);
            ac0[3] += __uint_as_float(v0.y & 0xffff0000u);
            ac0[4] += __uint_as_float(v0.z << 16);
            ac0[5] += __uint_as_float(v0.z & 0xffff0000u);
            ac0[6] += __uint_as_float(v0.w << 16);
            ac0[7] += __uint_as_float(v0.w & 0xffff0000u);
            ac1[0] += __uint_as_float(v1.x << 16);
            ac1[1] += __uint_as_float(v1.x & 0xffff0000u);
            ac1[2] += __uint_as_float(v1.y << 16);
            ac1[3] += __uint_as_float(v1.y & 0xffff0000u);
            ac1[4] += __uint_as_float(v1.z << 16);
            ac1[5] += __uint_as_float(v1.z & 0xffff0000u);
            ac1[6] += __uint_as_float(v1.w << 16);
            ac1[7] += __uint_as_float(v1.w & 0xffff0000u);
        }
        uint4 pk;
        pk.x = f2bf(clip01(ac0[0] + ac1[0])) | (f2bf(clip01(ac0[1] + ac1[1])) << 16);
        pk.y = f2bf(clip01(ac0[2] + ac1[2])) | (f2bf(clip01(ac0[3] + ac1[3])) << 16);
        pk.z = f2bf(clip01(ac0[4] + ac1[4])) | (f2bf(clip01(ac0[5] + ac1[5])) << 16);
        pk.w = f2bf(clip01(ac0[6] + ac1[6])) | (f2bf(clip01(ac0[7] + ac1[7])) << 16);
        const int colb = (side * 1024 + slice * 128 + li * 16) ^ ((p & 7) << 4);
        *(uint4*)((char*)xg + (size_t)(pblk + p) * 2048 + colb) = pk;
    }
}

// ---------------------------------------------------------------------------
// Kernel 2: MLP. x arrives already in the swizzled LDS layout -> linear 32KB
// stage. MFMA layer1 + layers 2/3 identical to r9/r10 (verified).
// ---------------------------------------------------------------------------
__global__ __launch_bounds__(256, 4) void mlp2(
    const unsigned int* __restrict__ xg,        // [NPOS][512] uints, swizzled
    const unsigned int* __restrict__ w1f,       // frag-ordered bf16
    const float* __restrict__ b1,
    const float* __restrict__ W2, const float* __restrict__ b2,
    const float* __restrict__ W3, const float* __restrict__ b3,
    float* __restrict__ out)
{
    __shared__ __align__(16) char smem[32768];
    char* xb   = smem;
    float* h1  = (float*)smem;                  // [16][132]
    float* w2  = (float*)smem + 16 * 132;       // [32][132]
    float* h2  = (float*)smem + 48 * 132;       // [16][33]

    const int t    = threadIdx.x;               // 0..255
    const int pblk = blockIdx.x * MT;
    const int w    = t >> 6;
    const int lane = t & 63;

    // ---- stage x tile: linear 32KB copy ----
    {
        const uint4* src = (const uint4*)((const char*)xg + (size_t)pblk * 2048);
#pragma unroll
        for (int i = 0; i < 8; ++i) {
            int f = t + i * 256;
            *(uint4*)(xb + f * 16) = src[f];
        }
    }
    __syncthreads();

    // ---- layer1 GEMM via MFMA (M=16, N=128, K=1024) ----
    const int l15 = lane & 15, lg = lane >> 4, lq = lane & 7;
    f32x4 acc0 = {}, acc1 = {};
    const int arow = l15 * 2048;
    const bf16x8* w1v = (const bf16x8*)w1f;
#pragma unroll 4
    for (int ks = 0; ks < 32; ++ks) {
        const int acol = (ks * 64 + lg * 16) ^ (lq << 4);
        bf16x8 a0  = *(const bf16x8*)(xb + arow + acol);
        bf16x8 bf0 = w1v[((2 * w + 0) * 32 + ks) * 64 + lane];
        bf16x8 bf1 = w1v[((2 * w + 1) * 32 + ks) * 64 + lane];
        acc0 = __builtin_amdgcn_mfma_f32_16x16x32_bf16(a0, bf0, acc0, 0, 0, 0);
        acc1 = __builtin_amdgcn_mfma_f32_16x16x32_bf16(a0, bf1, acc1, 0, 0, 0);
    }
    __syncthreads();   // x tile dead; smem becomes h1/w2/h2

    // ---- epilogue: bias + clip -> h1[16][132] ----
    {
        const int o0 = (2 * w + 0) * 16 + l15;
        const int o1 = (2 * w + 1) * 16 + l15;
        const float bb0 = b1[o0], bb1 = b1[o1];
#pragma unroll
        for (int r = 0; r < 4; ++r) {
            int p0 = lg * 4 + r;
            h1[p0 * 132 + o0] = clip01(acc0[r] + bb0);
            h1[p0 * 132 + o1] = clip01(acc1[r] + bb1);
        }
    }
    // stage W2 (32x128)
#pragma unroll
    for (int i = 0; i < 16; ++i) {
        int f = t + i * 256;
        int o = f >> 7, k = f & 127;
        w2[o * 132 + k] = W2[o * 128 + k];
    }
    __syncthreads();

    // ---- layer2: 16 pos x 32 out ----
    {
        const int p2 = t >> 4;
        const int ob = (t & 15) * 2;
        float s0 = b2[ob], s1 = b2[ob + 1];
#pragma unroll
        for (int k4 = 0; k4 < 32; ++k4) {
            float4 h4 = *(const float4*)(h1 + p2 * 132 + k4 * 4);
            float4 wa = *(const float4*)(w2 + ob * 132 + k4 * 4);
            float4 wb = *(const float4*)(w2 + (ob + 1) * 132 + k4 * 4);
            s0 += h4.x * wa.x + h4.y * wa.y + h4.z * wa.z + h4.w * wa.w;
            s1 += h4.x * wb.x + h4.y * wb.y + h4.z * wb.z + h4.w * wb.w;
        }
        h2[p2 * 33 + ob]     = clip01(s0);
        h2[p2 * 33 + ob + 1] = clip01(s1);
    }
    __syncthreads();

    // ---- layer3 + tanh ----
    if (t < MT) {
        float s = b3[0];
#pragma unroll
        for (int k = 0; k < 32; ++k) s += h2[t * 33 + k] * W3[k];
        out[pblk + t] = tanhf(s);
    }
}

// ---------------------------------------------------------------------------
extern "C" void kernel_launch(void* const* d_in, const int* in_sizes, int n_in,
                              void* d_out, int out_size, void* d_ws, size_t ws_size,
                              hipStream_t stream) {
    const int*   stm_idx  = (const int*)  d_in[0];
    const int*   nstm_idx = (const int*)  d_in[2];
    const float* emb      = (const float*)d_in[4];
    const float* W1       = (const float*)d_in[5];
    const float* b1       = (const float*)d_in[6];
    const float* W2       = (const float*)d_in[7];
    const float* b2       = (const float*)d_in[8];
    const float* W3       = (const float*)d_in[9];
    const float* b3       = (const float*)d_in[10];
    float*       out      = (float*)d_out;

    unsigned int* embbf = (unsigned int*)d_ws;                        // 41,943,040 B
    unsigned int* w1f   = (unsigned int*)((char*)d_ws + 41943040);    //    262,144 B
    unsigned int* xg    = (unsigned int*)((char*)d_ws + 42205184);    // 33,554,432 B

    cvt_emb<<<2048, 256, 0, stream>>>(emb, embbf);
    prep_w1<<<64, 256, 0, stream>>>(W1, w1f);
    gather_slices<<<2048, 256, 0, stream>>>(stm_idx, nstm_idx, embbf, xg);
    mlp2<<<NPOS / MT, 256, 0, stream>>>(xg, w1f, b1, W2, b2, W3, b3, out);
}

// Round 13
// 119.536 us; speedup vs baseline: 4.8877x; 4.8877x over previous
//
#include <hip/hip_runtime.h>
#include <math.h>

#define NPOS  16384
#define LBAG  30
#define NFEAT 40960
#define HDIM  512          // per side
#define MT    16           // positions per block (mlp2)

typedef short bf16x8 __attribute__((ext_vector_type(8)));
typedef float f32x4  __attribute__((ext_vector_type(4)));

__device__ __forceinline__ unsigned int f2bf(float f) {
    unsigned int u = __float_as_uint(f);
    return (u + 0x7fffu + ((u >> 16) & 1u)) >> 16;
}
__device__ __forceinline__ float clip01(float v) { return fminf(fmaxf(v, 0.f), 1.f); }

// ---------------------------------------------------------------------------
// Prep 1: emb fp32 -> bf16 single table [NFEAT][512] (uint pairs). ~20us.
// ---------------------------------------------------------------------------
__global__ __launch_bounds__(256) void cvt_emb(const float* __restrict__ src,
                                               unsigned int* __restrict__ dst) {
    const int nchunk = NFEAT * HDIM / 8;
    int c = blockIdx.x * 256 + threadIdx.x;
    const int stride = gridDim.x * 256;
    for (; c < nchunk; c += stride) {
        float4 f0 = ((const float4*)src)[(size_t)c * 2];
        float4 f1 = ((const float4*)src)[(size_t)c * 2 + 1];
        uint4 o;
        o.x = f2bf(f0.x) | (f2bf(f0.y) << 16);
        o.y = f2bf(f0.z) | (f2bf(f0.w) << 16);
        o.z = f2bf(f1.x) | (f2bf(f1.y) << 16);
        o.w = f2bf(f1.z) | (f2bf(f1.w) << 16);
        ((uint4*)dst)[c] = o;
    }
}

// ---------------------------------------------------------------------------
// Prep 2: W1 [128][1024] fp32 -> bf16 in MFMA B-fragment order.
//   B[k][j] = W1[j][k], j = nf*16 + (lane&15), k = ks*32 + (lane>>4)*8 + b
// ---------------------------------------------------------------------------
__global__ __launch_bounds__(256) void prep_w1(const float* __restrict__ W1,
                                               unsigned int* __restrict__ dst) {
    int c = blockIdx.x * 256 + threadIdx.x;
    if (c >= 8 * 32 * 64) return;
    int l  = c & 63;
    int ks = (c >> 6) & 31;
    int nf = c >> 11;
    int o  = nf * 16 + (l & 15);
    int kb = ks * 32 + (l >> 4) * 8;
    float4 f0 = *(const float4*)(W1 + (size_t)o * 1024 + kb);
    float4 f1 = *(const float4*)(W1 + (size_t)o * 1024 + kb + 4);
    uint4 v;
    v.x = f2bf(f0.x) | (f2bf(f0.y) << 16);
    v.y = f2bf(f0.z) | (f2bf(f0.w) << 16);
    v.z = f2bf(f1.x) | (f2bf(f1.y) << 16);
    v.w = f2bf(f1.z) | (f2bf(f1.w) << 16);
    ((uint4*)dst)[c] = v;
}

// ---------------------------------------------------------------------------
// Kernel 1, round 13: r10's XCD-sliced gather + dual accumulator chains,
// WITHOUT r12's __launch_bounds__(256,8). r12 post-mortem: the (256,8) bound
// made the allocator target 32 VGPR -> it SPILLED both acc arrays to scratch
// (WRITE_SIZE 32MB -> 1.06GB, dur 78 -> 553us). Dual chains need ~45 VGPR;
// anything <=64 keeps 8 waves/SIMD anyway, so the bound was pure downside.
// Theory unchanged from r12 (r7's ILP-null was measured in the pre-slicing
// fabric-bound regime and does not apply post-slicing): rows even/odd into
// independent ac0/ac1 chains lets the allocator keep 2+ loads in flight per
// wave at full 32-waves/CU occupancy.
// ---------------------------------------------------------------------------
__global__ __launch_bounds__(256) void gather_slices(
    const int* __restrict__ stm_idx, const int* __restrict__ nstm_idx,
    const unsigned int* __restrict__ embbf,     // [NFEAT][256] uints (512 bf16)
    unsigned int* __restrict__ xg)              // [NPOS][512] uints, swizzled
{
    __shared__ int sidx[3840];                  // 64 pos x 2 sides x 30
    const int t     = threadIdx.x;
    const int slice = blockIdx.x & 7;
    const int pblk  = (blockIdx.x >> 3) * 64;

    // stage indices, bag-major: sidx[(p*2+side)*30 + r]
#pragma unroll
    for (int i = 0; i < 15; ++i) {
        int e = t + i * 256;                    // 0..3839
        if (e < 1920) {
            int p = e / 30, r = e - p * 30;
            sidx[p * 60 + r] = stm_idx[(pblk + p) * 30 + r];
        } else {
            int e2 = e - 1920;
            int p = e2 / 30, r = e2 - p * 30;
            sidx[p * 60 + 30 + r] = nstm_idx[(pblk + p) * 30 + r];
        }
    }
    __syncthreads();

    const int lane = t & 63, w = t >> 6;
    const int g  = lane >> 3;                   // lane-group 0..7 (one bag)
    const int li = lane & 7;                    // 16B chunk within 128B line
    const unsigned int tabofs = slice * 32 + li * 4;

#pragma unroll 1
    for (int it = 0; it < 4; ++it) {
        const int bag  = it * 32 + w * 8 + g;   // 0..127
        const int p    = bag >> 1;
        const int side = bag & 1;
        const int* ids = sidx + bag * 30;       // banks 30g%32: all distinct
        float ac0[8], ac1[8];
#pragma unroll
        for (int j = 0; j < 8; ++j) { ac0[j] = 0.f; ac1[j] = 0.f; }
#pragma unroll
        for (int r = 0; r < 30; r += 2) {
            const int id0 = ids[r];
            const int id1 = ids[r + 1];
            const uint4 v0 = *(const uint4*)(embbf + (size_t)id0 * 256 + tabofs);
            const uint4 v1 = *(const uint4*)(embbf + (size_t)id1 * 256 + tabofs);
            ac0[0] += __uint_as_float(v0.x << 16);
            ac0[1] += __uint_as_float(v0.x & 0xffff0000u);
            ac0[2] += __uint_as_float(v0.y << 16);
            ac0[3] += __uint_as_float(v0.y & 0xffff0000u);
            ac0[4] += __uint_as_float(v0.z << 16);
            ac0[5] += __uint_as_float(v0.z & 0xffff0000u);
            ac0[6] += __uint_as_float(v0.w << 16);
            ac0[7] += __uint_as_float(v0.w & 0xffff0000u);
            ac1[0] += __uint_as_float(v1.x << 16);
            ac1[1] += __uint_as_float(v1.x & 0xffff0000u);
            ac1[2] += __uint_as_float(v1.y << 16);
            ac1[3] += __uint_as_float(v1.y & 0xffff0000u);
            ac1[4] += __uint_as_float(v1.z << 16);
            ac1[5] += __uint_as_float(v1.z & 0xffff0000u);
            ac1[6] += __uint_as_float(v1.w << 16);
            ac1[7] += __uint_as_float(v1.w & 0xffff0000u);
        }
        uint4 pk;
        pk.x = f2bf(clip01(ac0[0] + ac1[0])) | (f2bf(clip01(ac0[1] + ac1[1])) << 16);
        pk.y = f2bf(clip01(ac0[2] + ac1[2])) | (f2bf(clip01(ac0[3] + ac1[3])) << 16);
        pk.z = f2bf(clip01(ac0[4] + ac1[4])) | (f2bf(clip01(ac0[5] + ac1[5])) << 16);
        pk.w = f2bf(clip01(ac0[6] + ac1[6])) | (f2bf(clip01(ac0[7] + ac1[7])) << 16);
        const int colb = (side * 1024 + slice * 128 + li * 16) ^ ((p & 7) << 4);
        *(uint4*)((char*)xg + (size_t)(pblk + p) * 2048 + colb) = pk;
    }
}

// ---------------------------------------------------------------------------
// Kernel 2: MLP. x arrives already in the swizzled LDS layout -> linear 32KB
// stage. MFMA layer1 + layers 2/3 identical to r9/r10 (verified).
// ---------------------------------------------------------------------------
__global__ __launch_bounds__(256, 4) void mlp2(
    const unsigned int* __restrict__ xg,        // [NPOS][512] uints, swizzled
    const unsigned int* __restrict__ w1f,       // frag-ordered bf16
    const float* __restrict__ b1,
    const float* __restrict__ W2, const float* __restrict__ b2,
    const float* __restrict__ W3, const float* __restrict__ b3,
    float* __restrict__ out)
{
    __shared__ __align__(16) char smem[32768];
    char* xb   = smem;
    float* h1  = (float*)smem;                  // [16][132]
    float* w2  = (float*)smem + 16 * 132;       // [32][132]
    float* h2  = (float*)smem + 48 * 132;       // [16][33]

    const int t    = threadIdx.x;               // 0..255
    const int pblk = blockIdx.x * MT;
    const int w    = t >> 6;
    const int lane = t & 63;

    // ---- stage x tile: linear 32KB copy ----
    {
        const uint4* src = (const uint4*)((const char*)xg + (size_t)pblk * 2048);
#pragma unroll
        for (int i = 0; i < 8; ++i) {
            int f = t + i * 256;
            *(uint4*)(xb + f * 16) = src[f];
        }
    }
    __syncthreads();

    // ---- layer1 GEMM via MFMA (M=16, N=128, K=1024) ----
    const int l15 = lane & 15, lg = lane >> 4, lq = lane & 7;
    f32x4 acc0 = {}, acc1 = {};
    const int arow = l15 * 2048;
    const bf16x8* w1v = (const bf16x8*)w1f;
#pragma unroll 4
    for (int ks = 0; ks < 32; ++ks) {
        const int acol = (ks * 64 + lg * 16) ^ (lq << 4);
        bf16x8 a0  = *(const bf16x8*)(xb + arow + acol);
        bf16x8 bf0 = w1v[((2 * w + 0) * 32 + ks) * 64 + lane];
        bf16x8 bf1 = w1v[((2 * w + 1) * 32 + ks) * 64 + lane];
        acc0 = __builtin_amdgcn_mfma_f32_16x16x32_bf16(a0, bf0, acc0, 0, 0, 0);
        acc1 = __builtin_amdgcn_mfma_f32_16x16x32_bf16(a0, bf1, acc1, 0, 0, 0);
    }
    __syncthreads();   // x tile dead; smem becomes h1/w2/h2

    // ---- epilogue: bias + clip -> h1[16][132] ----
    {
        const int o0 = (2 * w + 0) * 16 + l15;
        const int o1 = (2 * w + 1) * 16 + l15;
        const float bb0 = b1[o0], bb1 = b1[o1];
#pragma unroll
        for (int r = 0; r < 4; ++r) {
            int p0 = lg * 4 + r;
            h1[p0 * 132 + o0] = clip01(acc0[r] + bb0);
            h1[p0 * 132 + o1] = clip01(acc1[r] + bb1);
        }
    }
    // stage W2 (32x128)
#pragma unroll
    for (int i = 0; i < 16; ++i) {
        int f = t + i * 256;
        int o = f >> 7, k = f & 127;
        w2[o * 132 + k] = W2[o * 128 + k];
    }
    __syncthreads();

    // ---- layer2: 16 pos x 32 out ----
    {
        const int p2 = t >> 4;
        const int ob = (t & 15) * 2;
        float s0 = b2[ob], s1 = b2[ob + 1];
#pragma unroll
        for (int k4 = 0; k4 < 32; ++k4) {
            float4 h4 = *(const float4*)(h1 + p2 * 132 + k4 * 4);
            float4 wa = *(const float4*)(w2 + ob * 132 + k4 * 4);
            float4 wb = *(const float4*)(w2 + (ob + 1) * 132 + k4 * 4);
            s0 += h4.x * wa.x + h4.y * wa.y + h4.z * wa.z + h4.w * wa.w;
            s1 += h4.x * wb.x + h4.y * wb.y + h4.z * wb.z + h4.w * wb.w;
        }
        h2[p2 * 33 + ob]     = clip01(s0);
        h2[p2 * 33 + ob + 1] = clip01(s1);
    }
    __syncthreads();

    // ---- layer3 + tanh ----
    if (t < MT) {
        float s = b3[0];
#pragma unroll
        for (int k = 0; k < 32; ++k) s += h2[t * 33 + k] * W3[k];
        out[pblk + t] = tanhf(s);
    }
}

// ---------------------------------------------------------------------------
extern "C" void kernel_launch(void* const* d_in, const int* in_sizes, int n_in,
                              void* d_out, int out_size, void* d_ws, size_t ws_size,
                              hipStream_t stream) {
    const int*   stm_idx  = (const int*)  d_in[0];
    const int*   nstm_idx = (const int*)  d_in[2];
    const float* emb      = (const float*)d_in[4];
    const float* W1       = (const float*)d_in[5];
    const float* b1       = (const float*)d_in[6];
    const float* W2       = (const float*)d_in[7];
    const float* b2       = (const float*)d_in[8];
    const float* W3       = (const float*)d_in[9];
    const float* b3       = (const float*)d_in[10];
    float*       out      = (float*)d_out;

    unsigned int* embbf = (unsigned int*)d_ws;                        // 41,943,040 B
    unsigned int* w1f   = (unsigned int*)((char*)d_ws + 41943040);    //    262,144 B
    unsigned int* xg    = (unsigned int*)((char*)d_ws + 42205184);    // 33,554,432 B

    cvt_emb<<<2048, 256, 0, stream>>>(emb, embbf);
    prep_w1<<<64, 256, 0, stream>>>(W1, w1f);
    gather_slices<<<2048, 256, 0, stream>>>(stm_idx, nstm_idx, embbf, xg);
    mlp2<<<NPOS / MT, 256, 0, stream>>>(xg, w1f, b1, W2, b2, W3, b3, out);
}

// Round 14
// 113.156 us; speedup vs baseline: 5.1633x; 1.0564x over previous
//
#include <hip/hip_runtime.h>
#include <math.h>

#define NPOS  16384
#define LBAG  30
#define NFEAT 40960
#define HDIM  512          // per side
#define MT    16           // positions per block (mlp2)
#define THR   20480        // id-range phase split (half the table)

typedef short bf16x8 __attribute__((ext_vector_type(8)));
typedef float f32x4  __attribute__((ext_vector_type(4)));

__device__ __forceinline__ unsigned int f2bf(float f) {
    unsigned int u = __float_as_uint(f);
    return (u + 0x7fffu + ((u >> 16) & 1u)) >> 16;
}
__device__ __forceinline__ float clip01(float v) { return fminf(fmaxf(v, 0.f), 1.f); }

// ---------------------------------------------------------------------------
// Prep 1: emb fp32 -> bf16 single table [NFEAT][512] (uint pairs). ~20us.
// ---------------------------------------------------------------------------
__global__ __launch_bounds__(256) void cvt_emb(const float* __restrict__ src,
                                               unsigned int* __restrict__ dst) {
    const int nchunk = NFEAT * HDIM / 8;
    int c = blockIdx.x * 256 + threadIdx.x;
    const int stride = gridDim.x * 256;
    for (; c < nchunk; c += stride) {
        float4 f0 = ((const float4*)src)[(size_t)c * 2];
        float4 f1 = ((const float4*)src)[(size_t)c * 2 + 1];
        uint4 o;
        o.x = f2bf(f0.x) | (f2bf(f0.y) << 16);
        o.y = f2bf(f0.z) | (f2bf(f0.w) << 16);
        o.z = f2bf(f1.x) | (f2bf(f1.y) << 16);
        o.w = f2bf(f1.z) | (f2bf(f1.w) << 16);
        ((uint4*)dst)[c] = o;
    }
}

// ---------------------------------------------------------------------------
// Prep 2: W1 [128][1024] fp32 -> bf16 in MFMA B-fragment order.
//   B[k][j] = W1[j][k], j = nf*16 + (lane&15), k = ks*32 + (lane>>4)*8 + b
// ---------------------------------------------------------------------------
__global__ __launch_bounds__(256) void prep_w1(const float* __restrict__ W1,
                                               unsigned int* __restrict__ dst) {
    int c = blockIdx.x * 256 + threadIdx.x;
    if (c >= 8 * 32 * 64) return;
    int l  = c & 63;
    int ks = (c >> 6) & 31;
    int nf = c >> 11;
    int o  = nf * 16 + (l & 15);
    int kb = ks * 32 + (l >> 4) * 8;
    float4 f0 = *(const float4*)(W1 + (size_t)o * 1024 + kb);
    float4 f1 = *(const float4*)(W1 + (size_t)o * 1024 + kb + 4);
    uint4 v;
    v.x = f2bf(f0.x) | (f2bf(f0.y) << 16);
    v.y = f2bf(f0.z) | (f2bf(f0.w) << 16);
    v.z = f2bf(f1.x) | (f2bf(f1.y) << 16);
    v.w = f2bf(f1.z) | (f2bf(f1.w) << 16);
    ((uint4*)dst)[c] = v;
}

// ---------------------------------------------------------------------------
// Kernel 1, round 14: XCD-sliced gather + TEMPORAL id-range phase split.
// r13 evidence: throughput tracks outstanding-lines/CU (r10 32wavesx1.5 ==
// r13 16wavesx3-4 == ~80us); pushing outstanding past ~50 is null (r11).
// Remaining term is SERVICE LATENCY: each XCD slice is 5.25MB vs 4MB L2
// (+3.9MB index stream) -> ~100MB capacity misses to L3 (FETCH 155MB).
// Fix: partition each bag's ids into <THR / >=THR lists at staging; gather
// all low rows (phase A, acc in 32 persistent regs), __syncthreads, then all
// high rows. Per-phase table working set 2.56MB < 4MB L2 -> L2-resident ->
// latency ~halves -> throughput ~doubles at fixed outstanding.
// Reassociation of the fp32 bag sum: ~1e-7, irrelevant vs 2e-3 bf16 floor.
// LDS: sidx u16[128][32]=8KB + nlo[128]=512B -> 8.7KB, 8 blocks/CU kept.
// ---------------------------------------------------------------------------
__global__ __launch_bounds__(256) void gather_slices(
    const int* __restrict__ stm_idx, const int* __restrict__ nstm_idx,
    const unsigned int* __restrict__ embbf,     // [NFEAT][256] uints (512 bf16)
    unsigned int* __restrict__ xg)              // [NPOS][512] uints, swizzled
{
    __shared__ unsigned short sidx16[128 * 32]; // per bag: lo ids up, hi ids down
    __shared__ int nlo[128];

    const int t     = threadIdx.x;
    const int slice = blockIdx.x & 7;
    const int pblk  = (blockIdx.x >> 3) * 64;

    // ---- stage + partition indices (thread b -> bag b) ----
    if (t < 128) {
        const int p    = t >> 1;
        const int side = t & 1;
        const int* src = (side ? nstm_idx : stm_idx) + (size_t)(pblk + p) * 30;
        unsigned short* d = sidx16 + t * 32;
        int lo = 0, hi = 29;
#pragma unroll
        for (int r = 0; r < 30; ++r) {
            const int id = src[r];
            if (id < THR) d[lo++] = (unsigned short)id;
            else          d[hi--] = (unsigned short)id;
        }
        nlo[t] = lo;
    }
    __syncthreads();

    const int lane = t & 63, w = t >> 6;
    const int g  = lane >> 3;                   // lane-group 0..7 (one bag)
    const int li = lane & 7;                    // 16B chunk within 128B line
    const unsigned int tabofs = slice * 32 + li * 4;

    float ac[4][8];
#pragma unroll
    for (int it = 0; it < 4; ++it)
#pragma unroll
        for (int j = 0; j < 8; ++j) ac[it][j] = 0.f;

#define ACCUM(it)                                                             \
    do {                                                                      \
        const unsigned int id = ids[r];                                       \
        const uint4 v = *(const uint4*)(embbf + (size_t)id * 256 + tabofs);   \
        ac[it][0] += __uint_as_float(v.x << 16);                              \
        ac[it][1] += __uint_as_float(v.x & 0xffff0000u);                      \
        ac[it][2] += __uint_as_float(v.y << 16);                              \
        ac[it][3] += __uint_as_float(v.y & 0xffff0000u);                      \
        ac[it][4] += __uint_as_float(v.z << 16);                              \
        ac[it][5] += __uint_as_float(v.z & 0xffff0000u);                      \
        ac[it][6] += __uint_as_float(v.w << 16);                              \
        ac[it][7] += __uint_as_float(v.w & 0xffff0000u);                      \
    } while (0)

    // ---- PHASE A: low-id rows (table rows [0,THR) = 2.56MB/XCD slice) ----
#pragma unroll
    for (int it = 0; it < 4; ++it) {
        const int bag = it * 32 + w * 8 + g;
        const unsigned short* ids = sidx16 + bag * 32;
        const int n = nlo[bag];
        for (int r = 0; r < n; ++r) ACCUM(it);
    }
    __syncthreads();    // align phases within block (chip-wide: co-residency)

    // ---- PHASE B: high-id rows + writeout ----
#pragma unroll
    for (int it = 0; it < 4; ++it) {
        const int bag = it * 32 + w * 8 + g;
        const unsigned short* ids = sidx16 + bag * 32;
        const int n = nlo[bag];
        for (int r = n; r < 30; ++r) ACCUM(it);

        const int p    = bag >> 1;
        const int side = bag & 1;
        uint4 pk;
        pk.x = f2bf(clip01(ac[it][0])) | (f2bf(clip01(ac[it][1])) << 16);
        pk.y = f2bf(clip01(ac[it][2])) | (f2bf(clip01(ac[it][3])) << 16);
        pk.z = f2bf(clip01(ac[it][4])) | (f2bf(clip01(ac[it][5])) << 16);
        pk.w = f2bf(clip01(ac[it][6])) | (f2bf(clip01(ac[it][7])) << 16);
        const int colb = (side * 1024 + slice * 128 + li * 16) ^ ((p & 7) << 4);
        *(uint4*)((char*)xg + (size_t)(pblk + p) * 2048 + colb) = pk;
    }
#undef ACCUM
}

// ---------------------------------------------------------------------------
// Kernel 2: MLP. x arrives already in the swizzled LDS layout -> linear 32KB
// stage. MFMA layer1 + layers 2/3 identical to r9-r13 (verified).
// ---------------------------------------------------------------------------
__global__ __launch_bounds__(256, 4) void mlp2(
    const unsigned int* __restrict__ xg,        // [NPOS][512] uints, swizzled
    const unsigned int* __restrict__ w1f,       // frag-ordered bf16
    const float* __restrict__ b1,
    const float* __restrict__ W2, const float* __restrict__ b2,
    const float* __restrict__ W3, const float* __restrict__ b3,
    float* __restrict__ out)
{
    __shared__ __align__(16) char smem[32768];
    char* xb   = smem;
    float* h1  = (float*)smem;                  // [16][132]
    float* w2  = (float*)smem + 16 * 132;       // [32][132]
    float* h2  = (float*)smem + 48 * 132;       // [16][33]

    const int t    = threadIdx.x;               // 0..255
    const int pblk = blockIdx.x * MT;
    const int w    = t >> 6;
    const int lane = t & 63;

    // ---- stage x tile: linear 32KB copy ----
    {
        const uint4* src = (const uint4*)((const char*)xg + (size_t)pblk * 2048);
#pragma unroll
        for (int i = 0; i < 8; ++i) {
            int f = t + i * 256;
            *(uint4*)(xb + f * 16) = src[f];
        }
    }
    __syncthreads();

    // ---- layer1 GEMM via MFMA (M=16, N=128, K=1024) ----
    const int l15 = lane & 15, lg = lane >> 4, lq = lane & 7;
    f32x4 acc0 = {}, acc1 = {};
    const int arow = l15 * 2048;
    const bf16x8* w1v = (const bf16x8*)w1f;
#pragma unroll 4
    for (int ks = 0; ks < 32; ++ks) {
        const int acol = (ks * 64 + lg * 16) ^ (lq << 4);
        bf16x8 a0  = *(const bf16x8*)(xb + arow + acol);
        bf16x8 bf0 = w1v[((2 * w + 0) * 32 + ks) * 64 + lane];
        bf16x8 bf1 = w1v[((2 * w + 1) * 32 + ks) * 64 + lane];
        acc0 = __builtin_amdgcn_mfma_f32_16x16x32_bf16(a0, bf0, acc0, 0, 0, 0);
        acc1 = __builtin_amdgcn_mfma_f32_16x16x32_bf16(a0, bf1, acc1, 0, 0, 0);
    }
    __syncthreads();   // x tile dead; smem becomes h1/w2/h2

    // ---- epilogue: bias + clip -> h1[16][132] ----
    {
        const int o0 = (2 * w + 0) * 16 + l15;
        const int o1 = (2 * w + 1) * 16 + l15;
        const float bb0 = b1[o0], bb1 = b1[o1];
#pragma unroll
        for (int r = 0; r < 4; ++r) {
            int p0 = lg * 4 + r;
            h1[p0 * 132 + o0] = clip01(acc0[r] + bb0);
            h1[p0 * 132 + o1] = clip01(acc1[r] + bb1);
        }
    }
    // stage W2 (32x128)
#pragma unroll
    for (int i = 0; i < 16; ++i) {
        int f = t + i * 256;
        int o = f >> 7, k = f & 127;
        w2[o * 132 + k] = W2[o * 128 + k];
    }
    __syncthreads();

    // ---- layer2: 16 pos x 32 out ----
    {
        const int p2 = t >> 4;
        const int ob = (t & 15) * 2;
        float s0 = b2[ob], s1 = b2[ob + 1];
#pragma unroll
        for (int k4 = 0; k4 < 32; ++k4) {
            float4 h4 = *(const float4*)(h1 + p2 * 132 + k4 * 4);
            float4 wa = *(const float4*)(w2 + ob * 132 + k4 * 4);
            float4 wb = *(const float4*)(w2 + (ob + 1) * 132 + k4 * 4);
            s0 += h4.x * wa.x + h4.y * wa.y + h4.z * wa.z + h4.w * wa.w;
            s1 += h4.x * wb.x + h4.y * wb.y + h4.z * wb.z + h4.w * wb.w;
        }
        h2[p2 * 33 + ob]     = clip01(s0);
        h2[p2 * 33 + ob + 1] = clip01(s1);
    }
    __syncthreads();

    // ---- layer3 + tanh ----
    if (t < MT) {
        float s = b3[0];
#pragma unroll
        for (int k = 0; k < 32; ++k) s += h2[t * 33 + k] * W3[k];
        out[pblk + t] = tanhf(s);
    }
}

// ---------------------------------------------------------------------------
extern "C" void kernel_launch(void* const* d_in, const int* in_sizes, int n_in,
                              void* d_out, int out_size, void* d_ws, size_t ws_size,
                              hipStream_t stream) {
    const int*   stm_idx  = (const int*)  d_in[0];
    const int*   nstm_idx = (const int*)  d_in[2];
    const float* emb      = (const float*)d_in[4];
    const float* W1       = (const float*)d_in[5];
    const float* b1       = (const float*)d_in[6];
    const float* W2       = (const float*)d_in[7];
    const float* b2       = (const float*)d_in[8];
    const float* W3       = (const float*)d_in[9];
    const float* b3       = (const float*)d_in[10];
    float*       out      = (float*)d_out;

    unsigned int* embbf = (unsigned int*)d_ws;                        // 41,943,040 B
    unsigned int* w1f   = (unsigned int*)((char*)d_ws + 41943040);    //    262,144 B
    unsigned int* xg    = (unsigned int*)((char*)d_ws + 42205184);    // 33,554,432 B

    cvt_emb<<<2048, 256, 0, stream>>>(emb, embbf);
    prep_w1<<<64, 256, 0, stream>>>(W1, w1f);
    gather_slices<<<2048, 256, 0, stream>>>(stm_idx, nstm_idx, embbf, xg);
    mlp2<<<NPOS / MT, 256, 0, stream>>>(xg, w1f, b1, W2, b2, W3, b3, out);
}